// Round 2
// baseline (339.430 us; speedup 1.0000x reference)
//
#include <hip/hip_runtime.h>

// DepthDeformConv: modulated deformable conv 3x3, stride1 pad1 dil1
// input (4,64,128,128) f32, offset (4,18,128,128), mask (4,9,128,128),
// weight (64,64,3,3), bias (64). depth is UNUSED by the reference.
// out (4,64,128,128) f32.
//
// Round 1 re-run (round-0 bench died on a Trio infra error, no verdict):
// thread-per-pixel, o-split 2 (32 accumulators/thread). Weights read via
// wave-uniform indices -> scalar loads, inner 288-FMA block is v_fmac_f32
// with SGPR weight operand.

#define HH 128
#define WW 128
#define CC 64
#define OO 64
#define KK 9
#define HW (128 * 128)

__global__ __launch_bounds__(256)
void ddc_kernel(const float* __restrict__ input,
                const float* __restrict__ offset,
                const float* __restrict__ mask,
                const float* __restrict__ weight,
                const float* __restrict__ bias,
                float* __restrict__ out)
{
    const int p     = blockIdx.x * 256 + threadIdx.x;  // pixel id within whole tensor
    const int oBase = blockIdx.y * 32;                 // output-channel half
    const int b  = p >> 14;        // / (128*128)
    const int hw = p & (HW - 1);
    const int h  = hw >> 7;
    const int w  = hw & 127;

    // ---- precompute the 9 bilinear stencils (indices clamped, corner
    //      weights premultiplied by validity and mask) ----
    int   idx[KK][4];
    float cw[KK][4];
    const float* offB = offset + (size_t)b * 18 * HW + hw;
    const float* mskB = mask   + (size_t)b * 9  * HW + hw;

    #pragma unroll
    for (int k = 0; k < KK; ++k) {
        const float oy = offB[(2 * k)     * HW];
        const float ox = offB[(2 * k + 1) * HW];
        const float m  = mskB[k * HW];

        const float py = (float)(h - 1 + k / 3) + oy;
        const float px = (float)(w - 1 + k % 3) + ox;
        const float y0f = floorf(py);
        const float x0f = floorf(px);
        const int y0 = (int)y0f;
        const int x0 = (int)x0f;
        const float wy = py - y0f;
        const float wx = px - x0f;
        const int y1 = y0 + 1, x1 = x0 + 1;

        const bool vy0 = (y0 >= 0) && (y0 < HH);
        const bool vy1 = (y1 >= 0) && (y1 < HH);
        const bool vx0 = (x0 >= 0) && (x0 < WW);
        const bool vx1 = (x1 >= 0) && (x1 < WW);

        const int y0c = min(max(y0, 0), HH - 1);
        const int y1c = min(max(y1, 0), HH - 1);
        const int x0c = min(max(x0, 0), WW - 1);
        const int x1c = min(max(x1, 0), WW - 1);

        idx[k][0] = y0c * WW + x0c;
        idx[k][1] = y0c * WW + x1c;
        idx[k][2] = y1c * WW + x0c;
        idx[k][3] = y1c * WW + x1c;

        const float wy1 = 1.f - wy, wx1 = 1.f - wx;
        cw[k][0] = (vy0 && vx0) ? wy1 * wx1 * m : 0.f;
        cw[k][1] = (vy0 && vx1) ? wy1 * wx  * m : 0.f;
        cw[k][2] = (vy1 && vx0) ? wy  * wx1 * m : 0.f;
        cw[k][3] = (vy1 && vx1) ? wy  * wx  * m : 0.f;
    }

    float acc[32];
    #pragma unroll
    for (int i = 0; i < 32; ++i) acc[i] = 0.f;

    const float* planeB = input + (size_t)b * CC * HW;

    for (int c = 0; c < CC; ++c) {
        const float* pl = planeB + c * HW;

        // sample the 9 deformed taps for this channel
        float v[KK];
        #pragma unroll
        for (int k = 0; k < KK; ++k) {
            v[k] = cw[k][0] * pl[idx[k][0]]
                 + cw[k][1] * pl[idx[k][1]]
                 + cw[k][2] * pl[idx[k][2]]
                 + cw[k][3] * pl[idx[k][3]];
        }

        // acc[oi] += weight[(oBase+oi), c, k] * v[k]
        // index is wave-uniform -> scalar loads
        const float* wp = weight + ((size_t)oBase * CC + c) * KK;
        #pragma unroll
        for (int oi = 0; oi < 32; ++oi) {
            #pragma unroll
            for (int k = 0; k < KK; ++k) {
                acc[oi] += wp[(size_t)oi * CC * KK + k] * v[k];
            }
        }
    }

    float* outB = out + ((size_t)b * OO + oBase) * HW + hw;
    #pragma unroll
    for (int oi = 0; oi < 32; ++oi) {
        outB[oi * HW] = acc[oi] + bias[oBase + oi];
    }
}

extern "C" void kernel_launch(void* const* d_in, const int* in_sizes, int n_in,
                              void* d_out, int out_size, void* d_ws, size_t ws_size,
                              hipStream_t stream)
{
    const float* input  = (const float*)d_in[0];
    // d_in[1] = depth, unused by the reference
    const float* offset = (const float*)d_in[2];
    const float* mask   = (const float*)d_in[3];
    const float* weight = (const float*)d_in[4];
    const float* bias   = (const float*)d_in[5];
    float* out = (float*)d_out;

    const int B = in_sizes[0] / (CC * HW);           // = 4
    dim3 grid((unsigned)(B * HW / 256), 2);          // pixel-blocks x o-halves
    ddc_kernel<<<grid, dim3(256), 0, stream>>>(input, offset, mask, weight, bias, out);
}

// Round 3
// 163.129 us; speedup vs baseline: 2.0807x; 2.0807x over previous
//
#include <hip/hip_runtime.h>

// DepthDeformConv — round 3: NHWC bf16 + in-register MFMA fragments.
//
// Kernel 1 (prep): input NCHW f32 -> NHWC bf16 in ws; weight (O,C,3,3) f32
//   -> wT[o][kt*64+c] bf16 in ws.
// Kernel 2 (main): grid = 4b x 128h x 2 half-rows, 256 thr (4 waves).
//   Wave owns 16 pixels (n-tile). Lane (pixel = lane&15, k-chunk = lane>>4)
//   bilinearly samples 8 CONTIGUOUS channels per corner (uint4 = 8 bf16),
//   packs straight into the 16x16x32 bf16 MFMA B-fragment (no LDS, no
//   barriers). A-fragments (weights) are lane-uniform-hot loads from wT.
//   acc: 4 m-tiles (o=64) x f32x4. Epilogue: 4 o-rows x 16 w per store.

typedef __attribute__((ext_vector_type(8))) short bf16x8;
typedef __attribute__((ext_vector_type(4))) float f32x4;
typedef __attribute__((ext_vector_type(4))) unsigned int u32x4;

#define HH 128
#define WW 128
#define CC 64
#define OO 64
#define HW (128 * 128)

__device__ __forceinline__ unsigned f32_to_bf16_rne(float f) {
    unsigned u = __float_as_uint(f);
    return (u + 0x7FFFu + ((u >> 16) & 1u)) >> 16;
}

// ---------------- kernel 1: transpose+pack ----------------
__global__ __launch_bounds__(256)
void prep_kernel(const float* __restrict__ input,
                 const float* __restrict__ weight,
                 unsigned short* __restrict__ nhwc,
                 unsigned short* __restrict__ wT)
{
    const int tid = threadIdx.x;
    if (blockIdx.x < 512) {
        // one block per (b, y): 64c x 128x tile via LDS (uint per elem,
        // row stride 129 dwords -> conflict-free both phases)
        __shared__ unsigned tile[64][129];
        const int b = blockIdx.x >> 7;
        const int y = blockIdx.x & 127;
        #pragma unroll
        for (int it = 0; it < 32; ++it) {
            int flat = it * 256 + tid;
            int c = flat >> 7, x = flat & 127;
            float v = input[((b * 64 + c) * 128 + y) * 128 + x];
            tile[c][x] = f32_to_bf16_rne(v);
        }
        __syncthreads();
        #pragma unroll
        for (int it = 0; it < 32; ++it) {
            int flat = it * 256 + tid;
            int x = flat >> 6, c = flat & 63;
            nhwc[((b * 128 + y) * 128 + x) * 64 + c] = (unsigned short)tile[c][x];
        }
    } else {
        // weight repack: wT[o*576 + kt*64 + c] = weight[(o*64 + c)*9 + kt]
        for (int it = 0; it < 144; ++it) {
            int d = it * 256 + tid;          // 0..36863
            int o = d / 576, r = d % 576;
            int kt = r >> 6, c = r & 63;
            wT[d] = (unsigned short)f32_to_bf16_rne(weight[(o * 64 + c) * 9 + kt]);
        }
    }
}

// ---------------- kernel 2: fused sample + MFMA ----------------
__global__ __launch_bounds__(256, 4)
void ddc_mfma(const unsigned short* __restrict__ nhwc,
              const unsigned short* __restrict__ wT,
              const float* __restrict__ offset,
              const float* __restrict__ mask,
              const float* __restrict__ bias,
              float* __restrict__ out)
{
    const int blk  = blockIdx.x;           // 1024 = 4b * 128h * 2
    const int b    = blk >> 8;
    const int h    = (blk >> 1) & 127;
    const int half = blk & 1;
    const int tid  = threadIdx.x;
    const int wave = tid >> 6;
    const int lane = tid & 63;
    const int l15  = lane & 15;            // pixel within wave n-tile / o-col
    const int kq   = lane >> 4;            // k-chunk quad (0..3)
    const int wpix = half * 64 + wave * 16 + l15;   // w coordinate

    f32x4 acc[4];
    #pragma unroll
    for (int mt = 0; mt < 4; ++mt) acc[mt] = (f32x4){0.f, 0.f, 0.f, 0.f};

    const unsigned short* nb = nhwc + (size_t)b * HW * CC;

    #pragma unroll
    for (int kt = 0; kt < 9; ++kt) {
        // ---- stencil for (pixel, tap) ----
        const float oy = offset[((b * 18 + 2 * kt)     * 128 + h) * 128 + wpix];
        const float ox = offset[((b * 18 + 2 * kt + 1) * 128 + h) * 128 + wpix];
        const float m  = mask  [((b * 9  + kt)         * 128 + h) * 128 + wpix];
        const float py = (float)(h - 1 + kt / 3) + oy;
        const float px = (float)(wpix - 1 + kt % 3) + ox;
        const float y0f = floorf(py), x0f = floorf(px);
        const int y0 = (int)y0f, x0 = (int)x0f;
        const float wy = py - y0f, wx = px - x0f;
        const int y1 = y0 + 1, x1 = x0 + 1;
        const bool vy0 = (y0 >= 0) & (y0 < HH);
        const bool vy1 = (y1 >= 0) & (y1 < HH);
        const bool vx0 = (x0 >= 0) & (x0 < WW);
        const bool vx1 = (x1 >= 0) & (x1 < WW);
        const int y0c = min(max(y0, 0), HH - 1), y1c = min(max(y1, 0), HH - 1);
        const int x0c = min(max(x0, 0), WW - 1), x1c = min(max(x1, 0), WW - 1);
        const int i00 = (y0c * WW + x0c) * CC;
        const int i01 = (y0c * WW + x1c) * CC;
        const int i10 = (y1c * WW + x0c) * CC;
        const int i11 = (y1c * WW + x1c) * CC;
        const float wy1 = 1.f - wy, wx1 = 1.f - wx;
        const float c00 = (vy0 && vx0) ? wy1 * wx1 * m : 0.f;
        const float c01 = (vy0 && vx1) ? wy1 * wx  * m : 0.f;
        const float c10 = (vy1 && vx0) ? wy  * wx1 * m : 0.f;
        const float c11 = (vy1 && vx1) ? wy  * wx  * m : 0.f;

        #pragma unroll
        for (int ks = 0; ks < 2; ++ks) {
            const int c0 = ks * 32 + kq * 8;   // this lane's 8-channel chunk

            // 4 corner loads: 8 contiguous bf16 each
            const u32x4 w00 = *(const u32x4*)(nb + i00 + c0);
            const u32x4 w01 = *(const u32x4*)(nb + i01 + c0);
            const u32x4 w10 = *(const u32x4*)(nb + i10 + c0);
            const u32x4 w11 = *(const u32x4*)(nb + i11 + c0);

            // unpack + weighted sum (f32)
            float s[8];
            #pragma unroll
            for (int j = 0; j < 4; ++j) {
                const float a0 = __uint_as_float(w00[j] << 16);
                const float a1 = __uint_as_float(w00[j] & 0xFFFF0000u);
                const float b0 = __uint_as_float(w01[j] << 16);
                const float b1 = __uint_as_float(w01[j] & 0xFFFF0000u);
                const float d0 = __uint_as_float(w10[j] << 16);
                const float d1 = __uint_as_float(w10[j] & 0xFFFF0000u);
                const float e0 = __uint_as_float(w11[j] << 16);
                const float e1 = __uint_as_float(w11[j] & 0xFFFF0000u);
                s[2 * j]     = c00 * a0 + c01 * b0 + c10 * d0 + c11 * e0;
                s[2 * j + 1] = c00 * a1 + c01 * b1 + c10 * d1 + c11 * e1;
            }

            // pack to bf16x8 B-fragment (RNE)
            u32x4 pk;
            #pragma unroll
            for (int j = 0; j < 4; ++j) {
                pk[j] = f32_to_bf16_rne(s[2 * j]) | (f32_to_bf16_rne(s[2 * j + 1]) << 16);
            }
            const bf16x8 bfrag = __builtin_bit_cast(bf16x8, pk);

            // weight A-fragments + MFMA (D = A*B + C; m=o, n=pixel)
            const int kg = kt * 64 + c0;       // global K index of lane's chunk
            #pragma unroll
            for (int mt = 0; mt < 4; ++mt) {
                const bf16x8 afrag =
                    *(const bf16x8*)(wT + (size_t)(mt * 16 + l15) * 576 + kg);
                acc[mt] = __builtin_amdgcn_mfma_f32_16x16x32_bf16(afrag, bfrag, acc[mt], 0, 0, 0);
            }
        }
    }

    // ---- epilogue: C/D layout col=lane&15 (pixel), row=kq*4+reg (o) ----
    #pragma unroll
    for (int mt = 0; mt < 4; ++mt) {
        #pragma unroll
        for (int r = 0; r < 4; ++r) {
            const int o = mt * 16 + kq * 4 + r;
            out[((b * 64 + o) * 128 + h) * 128 + wpix] = acc[mt][r] + bias[o];
        }
    }
}

extern "C" void kernel_launch(void* const* d_in, const int* in_sizes, int n_in,
                              void* d_out, int out_size, void* d_ws, size_t ws_size,
                              hipStream_t stream)
{
    const float* input  = (const float*)d_in[0];
    // d_in[1] = depth, unused by the reference
    const float* offset = (const float*)d_in[2];
    const float* mask   = (const float*)d_in[3];
    const float* weight = (const float*)d_in[4];
    const float* bias   = (const float*)d_in[5];
    float* out = (float*)d_out;

    unsigned short* nhwc = (unsigned short*)d_ws;                    // 8.39 MB
    unsigned short* wT   = nhwc + (size_t)4 * HW * CC;               // 72 KB

    prep_kernel<<<dim3(513), dim3(256), 0, stream>>>(input, weight, nhwc, wT);
    ddc_mfma<<<dim3(1024), dim3(256), 0, stream>>>(nhwc, wT, offset, mask, bias, out);
}

// Round 4
// 159.799 us; speedup vs baseline: 2.1241x; 1.0208x over previous
//
#include <hip/hip_runtime.h>

// DepthDeformConv — round 4: latency-hiding rework.
//   prep: 1024 transpose blocks (uint4 NHWC stores) + 18 weight blocks
//         (round 3 had a single serial weight block + 2B stores).
//   main: stencils for all 9 taps hoisted to registers, then an explicit
//         depth-3 software pipeline over the 18 (kt,ks) gather groups so
//         ~12 corner loads stay in flight. launch_bounds(256,3) -> 170 VGPR.

typedef __attribute__((ext_vector_type(8))) short bf16x8;
typedef __attribute__((ext_vector_type(4))) float f32x4;
typedef __attribute__((ext_vector_type(4))) unsigned int u32x4;

#define HH 128
#define WW 128
#define CC 64
#define OO 64
#define HW (128 * 128)

__device__ __forceinline__ unsigned f32_to_bf16_rne(float f) {
    unsigned u = __float_as_uint(f);
    return (u + 0x7FFFu + ((u >> 16) & 1u)) >> 16;
}

// ---------------- kernel 1: transpose+pack ----------------
__global__ __launch_bounds__(256)
void prep_kernel(const float* __restrict__ input,
                 const float* __restrict__ weight,
                 unsigned short* __restrict__ nhwc,
                 unsigned short* __restrict__ wT)
{
    const int tid = threadIdx.x;
    const int blk = blockIdx.x;
    if (blk < 1024) {
        // one block per (b, y, x-half): 64c x 64x tile via LDS
        __shared__ unsigned tile[64][65];
        const int b  = blk >> 8;
        const int y  = (blk >> 1) & 127;
        const int xh = blk & 1;
        const int xbase = xh * 64;
        #pragma unroll
        for (int it = 0; it < 16; ++it) {
            int flat = it * 256 + tid;          // 0..4095
            int c = flat >> 6, x = flat & 63;
            float v = input[((b * 64 + c) * 128 + y) * 128 + xbase + x];
            tile[c][x] = f32_to_bf16_rne(v);
        }
        __syncthreads();
        #pragma unroll
        for (int it = 0; it < 2; ++it) {
            int item = it * 256 + tid;          // 0..511
            int x = item >> 3, cg = item & 7;   // cg = 8-channel group
            unsigned r0 = tile[cg * 8 + 0][x], r1 = tile[cg * 8 + 1][x];
            unsigned r2 = tile[cg * 8 + 2][x], r3 = tile[cg * 8 + 3][x];
            unsigned r4 = tile[cg * 8 + 4][x], r5 = tile[cg * 8 + 5][x];
            unsigned r6 = tile[cg * 8 + 6][x], r7 = tile[cg * 8 + 7][x];
            u32x4 pk;
            pk[0] = r0 | (r1 << 16); pk[1] = r2 | (r3 << 16);
            pk[2] = r4 | (r5 << 16); pk[3] = r6 | (r7 << 16);
            *(u32x4*)(nhwc + ((size_t)((b * 128 + y) * 128 + xbase + x)) * 64 + cg * 8) = pk;
        }
    } else {
        // weight repack spread over 18 blocks:
        // wT[o*576 + kt*64 + c] = weight[(o*64 + c)*9 + kt]
        const int wblk = blk - 1024;            // 0..17
        #pragma unroll
        for (int it = 0; it < 8; ++it) {
            int d = (wblk * 8 + it) * 256 + tid;   // 0..36863
            int o = d / 576, r = d % 576;
            int kt = r >> 6, c = r & 63;
            wT[d] = (unsigned short)f32_to_bf16_rne(weight[(o * 64 + c) * 9 + kt]);
        }
    }
}

// ---------------- kernel 2: fused sample + MFMA ----------------
__global__ __launch_bounds__(256, 3)
void ddc_mfma(const unsigned short* __restrict__ nhwc,
              const unsigned short* __restrict__ wT,
              const float* __restrict__ offset,
              const float* __restrict__ mask,
              const float* __restrict__ bias,
              float* __restrict__ out)
{
    const int blk  = blockIdx.x;           // 1024 = 4b * 128h * 2
    const int b    = blk >> 8;
    const int h    = (blk >> 1) & 127;
    const int half = blk & 1;
    const int tid  = threadIdx.x;
    const int wave = tid >> 6;
    const int lane = tid & 63;
    const int l15  = lane & 15;            // pixel within wave n-tile / o-col
    const int kq   = lane >> 4;            // k-chunk quad (0..3)
    const int wpix = half * 64 + wave * 16 + l15;   // w coordinate
    const int coff = kq * 8;

    // ---- phase 1: all 9 bilinear stencils into registers ----
    int   sidx[9][4];
    float scw[9][4];
    #pragma unroll
    for (int kt = 0; kt < 9; ++kt) {
        const float oy = offset[((b * 18 + 2 * kt)     * 128 + h) * 128 + wpix];
        const float ox = offset[((b * 18 + 2 * kt + 1) * 128 + h) * 128 + wpix];
        const float m  = mask  [((b * 9  + kt)         * 128 + h) * 128 + wpix];
        const float py = (float)(h - 1 + kt / 3) + oy;
        const float px = (float)(wpix - 1 + kt % 3) + ox;
        const float y0f = floorf(py), x0f = floorf(px);
        const int y0 = (int)y0f, x0 = (int)x0f;
        const float wy = py - y0f, wx = px - x0f;
        const int y1 = y0 + 1, x1 = x0 + 1;
        const bool vy0 = (y0 >= 0) & (y0 < HH);
        const bool vy1 = (y1 >= 0) & (y1 < HH);
        const bool vx0 = (x0 >= 0) & (x0 < WW);
        const bool vx1 = (x1 >= 0) & (x1 < WW);
        const int y0c = min(max(y0, 0), HH - 1), y1c = min(max(y1, 0), HH - 1);
        const int x0c = min(max(x0, 0), WW - 1), x1c = min(max(x1, 0), WW - 1);
        sidx[kt][0] = (y0c * WW + x0c) * CC;
        sidx[kt][1] = (y0c * WW + x1c) * CC;
        sidx[kt][2] = (y1c * WW + x0c) * CC;
        sidx[kt][3] = (y1c * WW + x1c) * CC;
        const float wy1 = 1.f - wy, wx1 = 1.f - wx;
        scw[kt][0] = (vy0 && vx0) ? wy1 * wx1 * m : 0.f;
        scw[kt][1] = (vy0 && vx1) ? wy1 * wx  * m : 0.f;
        scw[kt][2] = (vy1 && vx0) ? wy  * wx1 * m : 0.f;
        scw[kt][3] = (vy1 && vx1) ? wy  * wx  * m : 0.f;
    }

    f32x4 acc[4];
    #pragma unroll
    for (int mt = 0; mt < 4; ++mt) acc[mt] = (f32x4){0.f, 0.f, 0.f, 0.f};

    const unsigned short* nb = nhwc + (size_t)b * HW * CC;

    // ---- phase 2: depth-3 software pipeline over 18 (kt,ks) groups ----
    u32x4 buf[3][4];
    auto load_group = [&](int g, int slot) {
        const int kt = g >> 1;
        const int c0 = ((g & 1) << 5) + coff;
        buf[slot][0] = *(const u32x4*)(nb + sidx[kt][0] + c0);
        buf[slot][1] = *(const u32x4*)(nb + sidx[kt][1] + c0);
        buf[slot][2] = *(const u32x4*)(nb + sidx[kt][2] + c0);
        buf[slot][3] = *(const u32x4*)(nb + sidx[kt][3] + c0);
    };
    load_group(0, 0);
    load_group(1, 1);
    load_group(2, 2);

    #pragma unroll
    for (int g = 0; g < 18; ++g) {
        const int kt   = g >> 1;
        const int slot = g % 3;
        const u32x4 w00 = buf[slot][0], w01 = buf[slot][1];
        const u32x4 w10 = buf[slot][2], w11 = buf[slot][3];
        const float c00 = scw[kt][0], c01 = scw[kt][1];
        const float c10 = scw[kt][2], c11 = scw[kt][3];

        // refill the freed slot before the compute chain
        if (g + 3 < 18) load_group(g + 3, slot);

        float s[8];
        #pragma unroll
        for (int j = 0; j < 4; ++j) {
            const float a0 = __uint_as_float(w00[j] << 16);
            const float a1 = __uint_as_float(w00[j] & 0xFFFF0000u);
            const float b0 = __uint_as_float(w01[j] << 16);
            const float b1 = __uint_as_float(w01[j] & 0xFFFF0000u);
            const float d0 = __uint_as_float(w10[j] << 16);
            const float d1 = __uint_as_float(w10[j] & 0xFFFF0000u);
            const float e0 = __uint_as_float(w11[j] << 16);
            const float e1 = __uint_as_float(w11[j] & 0xFFFF0000u);
            s[2 * j]     = c00 * a0 + c01 * b0 + c10 * d0 + c11 * e0;
            s[2 * j + 1] = c00 * a1 + c01 * b1 + c10 * d1 + c11 * e1;
        }
        u32x4 pk;
        #pragma unroll
        for (int j = 0; j < 4; ++j) {
            pk[j] = f32_to_bf16_rne(s[2 * j]) | (f32_to_bf16_rne(s[2 * j + 1]) << 16);
        }
        const bf16x8 bfrag = __builtin_bit_cast(bf16x8, pk);

        const int kg = kt * 64 + ((g & 1) << 5) + coff;
        #pragma unroll
        for (int mt = 0; mt < 4; ++mt) {
            const bf16x8 afrag =
                *(const bf16x8*)(wT + (size_t)(mt * 16 + l15) * 576 + kg);
            acc[mt] = __builtin_amdgcn_mfma_f32_16x16x32_bf16(afrag, bfrag, acc[mt], 0, 0, 0);
        }
    }

    // ---- epilogue: C/D layout col=lane&15 (pixel), row=kq*4+reg (o) ----
    #pragma unroll
    for (int mt = 0; mt < 4; ++mt) {
        #pragma unroll
        for (int r = 0; r < 4; ++r) {
            const int o = mt * 16 + kq * 4 + r;
            out[((b * 64 + o) * 128 + h) * 128 + wpix] = acc[mt][r] + bias[o];
        }
    }
}

extern "C" void kernel_launch(void* const* d_in, const int* in_sizes, int n_in,
                              void* d_out, int out_size, void* d_ws, size_t ws_size,
                              hipStream_t stream)
{
    const float* input  = (const float*)d_in[0];
    // d_in[1] = depth, unused by the reference
    const float* offset = (const float*)d_in[2];
    const float* mask   = (const float*)d_in[3];
    const float* weight = (const float*)d_in[4];
    const float* bias   = (const float*)d_in[5];
    float* out = (float*)d_out;

    unsigned short* nhwc = (unsigned short*)d_ws;                    // 8.39 MB
    unsigned short* wT   = nhwc + (size_t)4 * HW * CC;               // 72 KB

    prep_kernel<<<dim3(1042), dim3(256), 0, stream>>>(input, weight, nhwc, wT);
    ddc_mfma<<<dim3(1024), dim3(256), 0, stream>>>(nhwc, wT, offset, mask, bias, out);
}